// Round 1
// baseline (208.655 us; speedup 1.0000x reference)
//
#include <hip/hip_runtime.h>
#include <cstdint>

// Problem constants (from the reference)
#define LL    200
#define QQ    21
#define MM    1024
#define START 133        // 2*L//3
#define NS    67         // L - START
#define RGH   0.01f
#define RGJ   0.01f

// ws layout:
//   [0, 1024)              : accumulator slots (3 x 64 fp32) + p2 block counter
//   [1024, +LL*MM*4)       : tokT (transposed tokens, [j][n])
//   [TOKT end, +SLAB)      : partial-logits slab [y][iIdx][a][n] (plain stores)
#define SLOT_J2  0
#define SLOT_E   64
#define SLOT_LZ  128
#define SLOT_CNT 192     // u32 "blocks done" counter for fused p2 epilogue
#define TOKT_OFF 1024
#define TOKT_BYTES ((size_t)LL * MM * 4)
#define SLAB_OFF (TOKT_OFF + TOKT_BYTES)
#define SLAB_BYTES ((size_t)2 * NS * QQ * MM * 4)
#define WS_FULL (SLAB_OFF + SLAB_BYTES)
#define WS_TOK  SLAB_OFF

// LDS tile: raw a-major copy of J[i, a, j0:j0+TJ, :]. TJ=8 -> plane = 168
// dwords (672 B, 16B-aligned):
//  - DMA: 42-lane global_load_lds(16B) fills a plane exactly
//  - gather: tile[a*PLANE + jl*21 + b] — lanes differ only in b -> <=21
//    distinct consecutive dwords -> conflict-free (measured 0 conflicts)
// NBUF=3 (pipeline depth 2): per-tile barrier uses a COUNTED vmcnt wait
// (T3+T4) so the next-next tile's DMA stays in flight across the barrier.
// 3 x 14112 B = 42336 B -> still 3 blocks/CU.
#define TJ 8
#define PLANE 168
#define TILE_FLOATS (QQ * PLANE)       // 14112 B/buffer
#define NBUF 3

// mega grid: p1 blocks first (long), jsum filler blocks after
#define NB_P1 (NS * 8)                 // 536
#define NB_JS 1024
#define NB_P2 (NS * 4)                 // 268 p2 blocks (256 thr each)

typedef const uint32_t __attribute__((address_space(1)))* gq_t;
typedef uint32_t __attribute__((address_space(3)))* lq_t;

__device__ __forceinline__ float block_reduce_sum_256(float v) {
  __shared__ float sm[4];
  #pragma unroll
  for (int off = 32; off > 0; off >>= 1) v += __shfl_down(v, off, 64);
  const int lane = threadIdx.x & 63;
  const int wv   = threadIdx.x >> 6;
  __syncthreads();
  if (lane == 0) sm[wv] = v;
  __syncthreads();
  float r = 0.0f;
  if (threadIdx.x == 0) r = sm[0] + sm[1] + sm[2] + sm[3];
  return r;  // valid in thread 0 only
}

// ---------------------------------------------------------------------------
// DMA one tile (21 a-planes) into LDS. Wave wv owns planes {wv, wv+4, ...}:
// wave0 issues 6 global_load_lds, waves1-3 issue 5 — these counts are the
// vmcnt immediates used at the barriers. <=3-float overread stays in-slice.
// ---------------------------------------------------------------------------
__device__ __forceinline__ void dma_tile(
    const float* __restrict__ Ji, int j0, int rem, int wv, int lane,
    float* __restrict__ tile) {
  const int nlanes = (rem * QQ + 3) >> 2;      // 42 for rem=8; >=6 always
  if (lane < nlanes) {
    for (int a = wv; a < QQ; a += 4) {
      const float* g = Ji + a * (LL * QQ) + j0 * QQ + lane * 4;
      __builtin_amdgcn_global_load_lds((gq_t)g, (lq_t)(tile + a * PLANE),
                                       16, 0, 0);
    }
  }
}

// Always issues exactly TJ loads (clamped to jend-1) so per-iteration vmem
// instruction counts are uniform -> constant vmcnt immediates.
__device__ __forceinline__ void tok_load(
    const int* __restrict__ tokT, const int* __restrict__ Xtok, int useT,
    int j0, int jend, int n, int (&bo)[TJ]) {
  #pragma unroll
  for (int k = 0; k < TJ; ++k) {
    int j = j0 + k;
    j = (j < jend) ? j : (jend - 1);
    const int b = useT ? tokT[j * MM + n] : Xtok[n * LL + j];
    bo[k] = k * QQ + b;
  }
}

__device__ __forceinline__ void gather_tile(
    const float* __restrict__ tile, const int (&bo)[TJ], int rem,
    float (&lg)[QQ]) {
  #pragma unroll
  for (int jl = 0; jl < TJ; ++jl) {
    if (jl >= rem) break;              // block-uniform
    const float* p = tile + bo[jl];
    #pragma unroll
    for (int a = 0; a < QQ; ++a) lg[a] += p[a * PLANE];
  }
}

// Counted-wait barrier: each wave waits only for its OWN dma(s+1) (and older)
// to land, leaving dma(s+2) [the 6/5 newest vmem ops] in flight across the
// barrier. asm "memory" clobber + sched_barrier(0) pin cross-barrier motion.
__device__ __forceinline__ void tile_barrier(int wv) {
  if (wv == 0) asm volatile("s_waitcnt vmcnt(6)" ::: "memory");
  else         asm volatile("s_waitcnt vmcnt(5)" ::: "memory");
  __builtin_amdgcn_s_barrier();
  __builtin_amdgcn_sched_barrier(0);
}

// ---------------------------------------------------------------------------
// p1 body: block = (site iI, j-half y, 256-seq chunk z). Triple-buffered DMA
// with counted vmcnt (no full drains in the steady-state loop); partial
// logits -> plain coalesced stores to the (y,iI) slab region.
// MONO=true: all j + logsumexp epilogue (fallback path).
// ---------------------------------------------------------------------------
template <bool MONO>
__device__ __forceinline__ void logz_body(
    const float* __restrict__ J, const int* __restrict__ tokT,
    const int* __restrict__ Xtok, int useT, const float* __restrict__ h,
    const float* __restrict__ w, float* __restrict__ slab,
    float* __restrict__ acc, int iI, int y, int z,
    float (*lds)[TILE_FLOATS]) {
  const int i  = START + iI;
  const int h0 = i >> 1;
  const int jbeg = MONO ? 0 : (y ? h0 : 0);
  const int jend = MONO ? i : (y ? i : h0);   // range length always >= 66
  const int t = threadIdx.x, lane = t & 63, wv = t >> 6;
  const int n = z * 256 + t;
  const float* Ji = J + (size_t)i * (QQ * LL * QQ);
  const int ntiles = (jend - jbeg + TJ - 1) / TJ;   // >= 9

  float lg[QQ];
  #pragma unroll
  for (int a = 0; a < QQ; ++a) lg[a] = 0.0f;
  int boc[TJ], bot[TJ];

  // Prologue: tiles 0,1 (both full: range >= 66). One full drain per block.
  tok_load(tokT, Xtok, useT, jbeg, jend, n, boc);
  dma_tile(Ji, jbeg, TJ, wv, lane, lds[0]);
  dma_tile(Ji, jbeg + TJ, TJ, wv, lane, lds[1]);
  asm volatile("s_waitcnt vmcnt(0)" ::: "memory");
  __builtin_amdgcn_s_barrier();
  __builtin_amdgcn_sched_barrier(0);

  int cur = 0;
  for (int s = 0; s < ntiles; ++s) {
    const int j0  = jbeg + s * TJ;
    const int rem = min(TJ, jend - j0);
    // prefetch tokens for tile s+1 (clamped -> uniform 8 loads)
    tok_load(tokT, Xtok, useT, j0 + TJ, jend, n, bot);
    // prefetch DMA for tile s+2 (past-the-end -> harmless re-read of jbeg
    // into a buffer that is never gathered; keeps counts uniform)
    {
      int j2 = j0 + 2 * TJ;
      int rem2 = min(TJ, jend - j2);
      if (rem2 <= 0) { j2 = jbeg; rem2 = TJ; }
      int nb = cur + 2; if (nb >= NBUF) nb -= NBUF;
      dma_tile(Ji, j2, rem2, wv, lane, lds[nb]);
    }
    gather_tile(lds[cur], boc, rem, lg);   // overlaps 2 tiles of in-flight DMA
    #pragma unroll
    for (int k = 0; k < TJ; ++k) boc[k] = bot[k];
    tile_barrier(wv);                      // counted wait — NO vmcnt(0) drain
    ++cur; if (cur == NBUF) cur = 0;
  }

  if (MONO) {
    const float* hi = h + i * QQ;
    float mx = -3.0e38f;
    #pragma unroll
    for (int a = 0; a < QQ; ++a) { lg[a] += hi[a]; mx = fmaxf(mx, lg[a]); }
    float sme = 0.0f;
    #pragma unroll
    for (int a = 0; a < QQ; ++a) sme += expf(lg[a] - mx);
    const float contrib = w[n] * (mx + logf(sme));
    const float tot = block_reduce_sum_256(contrib);
    if (t == 0) atomicAdd(acc + SLOT_LZ + (iI & 63), tot);
  } else {
    float* dst = slab + (((size_t)y * NS + iI) * QQ) * MM + n;
    #pragma unroll
    for (int a = 0; a < QQ; ++a) dst[a * MM] = lg[a];
  }
}

// ---------------------------------------------------------------------------
// jsum body: sum(J^2) stream + sum(J*fij) prefix rows, grid-strided by jb.
// ---------------------------------------------------------------------------
__device__ __forceinline__ void jsum_body(
    const float* __restrict__ J, const float* __restrict__ fij,
    float* __restrict__ acc, int jb) {
  const int t = threadIdx.x;
  const float4* __restrict__ J4 = (const float4*)J;
  float j2 = 0.0f;
  for (int f = jb * 256 + t; f < (LL * QQ * LL * QQ / 4); f += NB_JS * 256) {
    const float4 v = J4[f];
    j2 += v.x * v.x + v.y * v.y + v.z * v.z + v.w * v.w;
  }
  float e = 0.0f;
  for (int r = jb; r < NS * QQ; r += NB_JS) {
    const int iI = r / QQ;
    const int a  = r - iI * QQ;
    const int i  = START + iI;
    const size_t base = (size_t)i * (QQ * LL * QQ) + (size_t)a * (LL * QQ);
    const float4* __restrict__ Jb = (const float4*)(J + base);
    const float4* __restrict__ Fb = (const float4*)(fij + base);
    const int lim  = i * QQ;
    const int lim4 = lim >> 2;
    for (int f = t; f < lim4; f += 256) {
      const float4 v = Jb[f], u = Fb[f];
      e += v.x * u.x + v.y * u.y + v.z * u.z + v.w * u.w;
    }
    const int rem = lim & 3;
    if (t < rem) {
      const int p = lim4 * 4 + t;
      e += (J + base)[p] * (fij + base)[p];
    }
  }
  const float tj2 = block_reduce_sum_256(j2);
  const float te  = block_reduce_sum_256(e);
  if (t == 0) {
    atomicAdd(acc + SLOT_J2 + (jb & 63), tj2);
    atomicAdd(acc + SLOT_E  + (jb & 63), te);
  }
}

// ---------------------------------------------------------------------------
// Fused kernel: blocks [0, NB_P1) run p1 (LDS/latency-bound, long —
// dispatched first); blocks [NB_P1, NB_P1+NB_JS) run jsum (HBM-bound
// fillers). Disjoint pipes overlap on the same CUs; jsum fills p1's tail.
// ---------------------------------------------------------------------------
__global__ __launch_bounds__(256) void kern_mega(
    const float* __restrict__ J, const float* __restrict__ fij,
    const int* __restrict__ tokT, float* __restrict__ slab,
    float* __restrict__ acc) {
  __shared__ float lds[NBUF][TILE_FLOATS];
  const int bx = blockIdx.x;
  if (bx < NB_P1) {
    const int iI  = bx % NS;
    const int sub = bx / NS;           // 0..7
    logz_body<false>(J, tokT, nullptr, 1, nullptr, nullptr, slab, acc,
                     iI, sub & 1, sub >> 1, lds);
  } else {
    jsum_body(J, fij, acc, bx - NB_P1);
  }
}

// Fallback kernels (ws too small for slab)
__global__ __launch_bounds__(256) void kern_logz_mono(
    const float* __restrict__ J, const int* __restrict__ tokT,
    const int* __restrict__ Xtok, int useT, const float* __restrict__ h,
    const float* __restrict__ w, float* __restrict__ acc) {
  __shared__ float lds[NBUF][TILE_FLOATS];
  logz_body<true>(J, tokT, Xtok, useT, h, w, nullptr, acc,
                  blockIdx.x, 0, blockIdx.z, lds);
}

__global__ __launch_bounds__(256) void kern_jsum(
    const float* __restrict__ J, const float* __restrict__ fij,
    float* __restrict__ acc) {
  jsum_body(J, fij, acc, blockIdx.x);
}

// ---------------------------------------------------------------------------
// Phase 2 (fused epilogue): combine j-half partials, logsumexp, weighted sum;
// the LAST block to finish (atomic counter) runs the final combine, saving a
// kernel launch. Slot reads in the epilogue go through atomicAdd(p, 0.0f) to
// stay on the device-coherent path (per-XCD L2s are not cross-coherent).
// ---------------------------------------------------------------------------
__global__ __launch_bounds__(256) void kern_logz_p2(
    const float* __restrict__ slab, const float* __restrict__ h,
    const float* __restrict__ fi, const float* __restrict__ w,
    float* __restrict__ acc, float* __restrict__ out) {
  const int iI = blockIdx.x;
  const int t  = threadIdx.x;
  const int n  = blockIdx.y * 256 + t;
  const float* s0 = slab + ((size_t)iI * QQ) * MM + n;
  const float* s1 = slab + (((size_t)NS + iI) * QQ) * MM + n;
  const float* hi = h + (START + iI) * QQ;
  float lg[QQ];
  float mx = -3.0e38f;
  #pragma unroll
  for (int a = 0; a < QQ; ++a) {
    lg[a] = s0[a * MM] + s1[a * MM] + hi[a];
    mx = fmaxf(mx, lg[a]);
  }
  float sme = 0.0f;
  #pragma unroll
  for (int a = 0; a < QQ; ++a) sme += expf(lg[a] - mx);
  const float v = w[n] * (mx + logf(sme));
  const float tot = block_reduce_sum_256(v);
  if (t == 0)
    atomicAdd(acc + SLOT_LZ + (((iI << 2) | blockIdx.y) & 63), tot);

  // last-block final combine
  __threadfence();
  __shared__ unsigned last_s;
  if (t == 0) last_s = atomicAdd((unsigned*)(acc + SLOT_CNT), 1u);
  __syncthreads();
  if (last_s == NB_P2 - 1) {
    float sj2v = 0.0f, sev = 0.0f, slzv = 0.0f;
    if (t < 64) {
      sj2v = atomicAdd(acc + SLOT_J2 + t, 0.0f);
      sev  = atomicAdd(acc + SLOT_E  + t, 0.0f);
      slzv = atomicAdd(acc + SLOT_LZ + t, 0.0f);
    }
    const float sj2 = block_reduce_sum_256(sj2v);
    const float se  = block_reduce_sum_256(sev);
    const float slz = block_reduce_sum_256(slzv);
    float hs = 0.0f, eh = 0.0f, ws = 0.0f;
    for (int idx = t; idx < LL * QQ; idx += 256) {
      const float hv = h[idx];
      hs += hv * hv;
      if (idx >= START * QQ) eh += fi[idx] * hv;
    }
    for (int idx = t; idx < MM; idx += 256) ws += w[idx];
    const float ths = block_reduce_sum_256(hs);
    const float teh = block_reduce_sum_256(eh);
    const float tws = block_reduce_sum_256(ws);
    if (t == 0) {
      const float energy = teh + se;
      const float nll = slz / tws - energy;
      out[0] = nll + RGH * ths + RGJ * sj2;
      out[1] = nll;
    }
  }
}

// ---------------------------------------------------------------------------
// Token transpose (+ accumulator zeroing folded in: block 0 zeroes the 1 KB
// slot region, replacing the hipMemsetAsync node).
// ---------------------------------------------------------------------------
__global__ __launch_bounds__(256) void kern_tokT(
    const int* __restrict__ X, int* __restrict__ tokT,
    float* __restrict__ acc) {
  const int idx = blockIdx.x * 256 + threadIdx.x;
  if (blockIdx.x == 0) acc[threadIdx.x] = 0.0f;   // 256 floats = slots + cnt
  if (idx < LL * MM) {
    const int j = idx / MM;
    const int n = idx - j * MM;
    tokT[idx] = X[n * LL + j];
  }
}

// ---------------------------------------------------------------------------
// Final combine for fallback paths only.
// ---------------------------------------------------------------------------
__global__ __launch_bounds__(256) void kern_final(
    const float* __restrict__ h, const float* __restrict__ fi,
    const float* __restrict__ w, const float* __restrict__ acc,
    float* __restrict__ out) {
  const int t = threadIdx.x;
  const float sj2 = block_reduce_sum_256(t < 64 ? acc[SLOT_J2 + t] : 0.0f);
  const float se  = block_reduce_sum_256(t < 64 ? acc[SLOT_E + t] : 0.0f);
  const float slz = block_reduce_sum_256(t < 64 ? acc[SLOT_LZ + t] : 0.0f);
  float hs = 0.0f, eh = 0.0f, ws = 0.0f;
  for (int idx = t; idx < LL * QQ; idx += 256) {
    const float hv = h[idx];
    hs += hv * hv;
    if (idx >= START * QQ) eh += fi[idx] * hv;
  }
  for (int idx = t; idx < MM; idx += 256) ws += w[idx];
  const float ths = block_reduce_sum_256(hs);
  const float teh = block_reduce_sum_256(eh);
  const float tws = block_reduce_sum_256(ws);
  if (t == 0) {
    const float energy = teh + se;
    const float nll = slz / tws - energy;
    out[0] = nll + RGH * ths + RGJ * sj2;
    out[1] = nll;
  }
}

extern "C" void kernel_launch(void* const* d_in, const int* in_sizes, int n_in,
                              void* d_out, int out_size, void* d_ws, size_t ws_size,
                              hipStream_t stream) {
  const int*   Xtok = (const int*)  d_in[0];
  const float* wts  = (const float*)d_in[1];
  const float* fi   = (const float*)d_in[2];
  const float* fij  = (const float*)d_in[3];
  const float* h    = (const float*)d_in[4];
  const float* J    = (const float*)d_in[5];
  float* out  = (float*)d_out;
  float* acc  = (float*)d_ws;
  int*   tokT = (int*)((char*)d_ws + TOKT_OFF);
  float* slab = (float*)((char*)d_ws + SLAB_OFF);

  if (ws_size >= WS_FULL) {
    kern_tokT<<<(LL * MM + 255) / 256, 256, 0, stream>>>(Xtok, tokT, acc);
    kern_mega<<<NB_P1 + NB_JS, 256, 0, stream>>>(J, fij, tokT, slab, acc);
    kern_logz_p2<<<dim3(NS, 4), 256, 0, stream>>>(slab, h, fi, wts, acc, out);
  } else if (ws_size >= WS_TOK) {
    kern_tokT<<<(LL * MM + 255) / 256, 256, 0, stream>>>(Xtok, tokT, acc);
    kern_jsum<<<NB_JS, 256, 0, stream>>>(J, fij, acc);
    kern_logz_mono<<<dim3(NS, 1, 4), 256, 0, stream>>>(J, tokT, Xtok, 1, h, wts, acc);
    kern_final<<<1, 256, 0, stream>>>(h, fi, wts, acc, out);
  } else {
    hipMemsetAsync(d_ws, 0, 1024, stream);
    kern_jsum<<<NB_JS, 256, 0, stream>>>(J, fij, acc);
    kern_logz_mono<<<dim3(NS, 1, 4), 256, 0, stream>>>(J, nullptr, Xtok, 0, h, wts, acc);
    kern_final<<<1, 256, 0, stream>>>(h, fi, wts, acc, out);
  }
}

// Round 2
// 187.425 us; speedup vs baseline: 1.1133x; 1.1133x over previous
//
#include <hip/hip_runtime.h>
#include <cstdint>

// Problem constants (from the reference)
#define LL    200
#define QQ    21
#define MM    1024
#define START 133        // 2*L//3
#define NS    67         // L - START
#define RGH   0.01f
#define RGJ   0.01f

// ws layout:
//   [0, 1024)              : accumulator slots (3 x 64 fp32)
//   [1024, +TOKP)          : tokP packed tokens, 4 j per dword, [jq][n]
//                            (52 words: 50 real + 2 pad, pad never consumed)
//   [TOKP end, +SLAB)      : partial-logits slab [y][iIdx][a][n]
#define SLOT_J2  0
#define SLOT_E   64
#define SLOT_LZ  128
#define TOKP_W   52
#define TOKP_OFF 1024
#define TOKP_BYTES ((size_t)TOKP_W * MM * 4)
#define SLAB_OFF (TOKP_OFF + TOKP_BYTES)
#define SLAB_BYTES ((size_t)2 * NS * QQ * MM * 4)
#define WS_FULL (SLAB_OFF + SLAB_BYTES)
#define WS_TOK  SLAB_OFF

// LDS tile: raw a-major copy of J[i, a, j0:j0+TJ, :]. TJ=12 -> plane = 252
// dwords (1008 B = exactly 63 16B chunks):
//  - DMA: 63-lane global_load_lds(16B) fills a plane exactly
//  - gather: tile[a*PLANE + jl*21 + b] — lanes differ only in b -> <=21
//    distinct consecutive dwords -> conflict-free (measured 0 conflicts)
// NBUF=3, 512-thread blocks (8 waves): 3 x 21168 B = 63504 B -> 2 blocks/CU,
// 16 waves/CU (VGPR<=128), ~7 tiles per half-range (fewer barrier drains).
#define TJ 12
#define PLANE 252
#define TILE_FLOATS (QQ * PLANE)       // 5292 floats = 21168 B
#define NBUF 3
#define BT 512
#define NWAVE 8

// mega grid: p1 blocks first (long), jsum filler blocks after
#define NB_P1 (NS * 4)                 // 268: (iI, y in {0,1}, z in {0,1})
#define NB_JS 512

typedef const uint32_t __attribute__((address_space(1)))* gq_t;
typedef uint32_t __attribute__((address_space(3)))* lq_t;

template <int NW>
__device__ __forceinline__ float block_reduce_sum(float v) {
  __shared__ float sm[NW];
  #pragma unroll
  for (int off = 32; off > 0; off >>= 1) v += __shfl_down(v, off, 64);
  const int lane = threadIdx.x & 63;
  const int wv   = threadIdx.x >> 6;
  __syncthreads();
  if (lane == 0) sm[wv] = v;
  __syncthreads();
  float r = 0.0f;
  if (threadIdx.x == 0) {
    #pragma unroll
    for (int k = 0; k < NW; ++k) r += sm[k];
  }
  return r;  // valid in thread 0 only
}

// ---------------------------------------------------------------------------
// DMA one tile (21 a-planes) into LDS. Wave wv owns planes {wv, wv+8, ...}:
// waves 0-4 issue 3 global_load_lds, waves 5-7 issue 2. <=3-float overread
// stays inside the plane.
// ---------------------------------------------------------------------------
__device__ __forceinline__ void dma_tile(
    const float* __restrict__ Ji, int j0, int rem, int wv, int lane,
    float* __restrict__ tile) {
  const int nlanes = (rem * QQ + 3) >> 2;      // 63 for rem=12
  if (lane < nlanes) {
    for (int a = wv; a < QQ; a += NWAVE) {
      const float* g = Ji + a * (LL * QQ) + j0 * QQ + lane * 4;
      __builtin_amdgcn_global_load_lds((gq_t)g, (lq_t)(tile + a * PLANE),
                                       16, 0, 0);
    }
  }
}

// ---------------------------------------------------------------------------
// Load the 3 packed token words covering tile at j0 (12 j's, j0 % 4 == 0).
// Always exactly 3 vmem instructions (distinct addresses -> no CSE):
//   USET=1: 3 x dword from tokP;  USET=0: 3 x dwordx4 from X, packed in VALU.
// Fully-fake tiles (j0 >= jend) reload tile-0's words.
// ---------------------------------------------------------------------------
template <int USET>
__device__ __forceinline__ void tok_words(
    const uint32_t* __restrict__ tokP, const int* __restrict__ Xtok,
    int j0, int jbeg, int jend, int n, uint32_t (&tw)[3]) {
  const int wbase = ((j0 < jend) ? j0 : jbeg) >> 2;
  #pragma unroll
  for (int wi = 0; wi < 3; ++wi) {
    int wq = wbase + wi;
    if constexpr (USET) {
      tw[wi] = tokP[wq * MM + n];        // words 50/51 = pad, never consumed
    } else {
      if (wq >= LL / 4) wq -= (LL / 4 - 1);   // 50->1, 51->2: in-bounds, distinct
      const int4 x = *reinterpret_cast<const int4*>(Xtok + n * LL + 4 * wq);
      tw[wi] = (uint32_t)x.x | ((uint32_t)x.y << 8)
             | ((uint32_t)x.z << 16) | ((uint32_t)x.w << 24);
    }
  }
}

// Counted-wait barrier. Immediate = vmem issued per iteration (d + 3 tokens):
// drains ALL prior-iteration vmem (incl. dma(s+1)) regardless of the
// compiler's intra-iteration issue order, while keeping this iteration's
// dma(s+2)+tok(s+2) in flight across the barrier (depth-2 pipeline).
__device__ __forceinline__ void tile_barrier(int wv) {
  if (wv < 5) asm volatile("s_waitcnt vmcnt(6)" ::: "memory");
  else        asm volatile("s_waitcnt vmcnt(5)" ::: "memory");
  __builtin_amdgcn_s_barrier();
  __builtin_amdgcn_sched_barrier(0);
}

// ---------------------------------------------------------------------------
// p1 body: block = (site iI, j-half y, 512-seq chunk z). Triple-buffered DMA,
// depth-2 token prefetch (packed words), unpack AFTER the gather so the token
// wait never serializes against the J-DMA queue.
// MONO=true: all j + logsumexp epilogue (fallback path).
// ---------------------------------------------------------------------------
template <bool MONO, int USET>
__device__ __forceinline__ void logz_body(
    const float* __restrict__ J, const uint32_t* __restrict__ tokP,
    const int* __restrict__ Xtok, const float* __restrict__ h,
    const float* __restrict__ w, float* __restrict__ slab,
    float* __restrict__ acc, int iI, int y, int z,
    float (*lds)[TILE_FLOATS]) {
  const int i   = START + iI;
  const int h0a = (i >> 1) & ~3;              // 4-aligned split for packed toks
  const int jbeg = MONO ? 0 : (y ? h0a : 0);
  const int jend = MONO ? i : (y ? i : h0a);  // range length always >= 64
  const int t = threadIdx.x, lane = t & 63, wv = t >> 6;
  const int n = z * BT + t;
  const float* Ji = J + (size_t)i * (QQ * LL * QQ);
  const int ntiles = (jend - jbeg + TJ - 1) / TJ;   // >= 6

  float lg[QQ];
  #pragma unroll
  for (int a = 0; a < QQ; ++a) lg[a] = 0.0f;

  uint32_t tw0[3], twc[3], twn[3];
  int bo[TJ];

  // Prologue: dma tiles 0,1; token words tiles 0,1; bo(tile0). One full
  // drain per block (order-robust), then steady counted waits only.
  dma_tile(Ji, jbeg, TJ, wv, lane, lds[0]);
  dma_tile(Ji, jbeg + TJ, TJ, wv, lane, lds[1]);
  tok_words<USET>(tokP, Xtok, jbeg, jbeg, jend, n, tw0);
  tok_words<USET>(tokP, Xtok, jbeg + TJ, jbeg, jend, n, twc);
  #pragma unroll
  for (int k = 0; k < TJ; ++k)
    bo[k] = k * QQ + (int)((tw0[k >> 2] >> ((k & 3) * 8)) & 0xFF);
  asm volatile("s_waitcnt vmcnt(0)" ::: "memory");
  __builtin_amdgcn_s_barrier();
  __builtin_amdgcn_sched_barrier(0);

  int cur = 0;
  for (int s = 0; s < ntiles; ++s) {
    const int j0  = jbeg + s * TJ;
    const int rem = min(TJ, jend - j0);
    // dma tile s+2 (past-the-end -> harmless re-read of tile 0 into a buffer
    // that is never gathered; keeps per-wave vmem counts uniform)
    {
      int j2 = j0 + 2 * TJ;
      int rem2 = jend - j2;
      if (rem2 <= 0) { j2 = jbeg; rem2 = TJ; } else if (rem2 > TJ) rem2 = TJ;
      int nb = cur + 2; if (nb >= NBUF) nb -= NBUF;
      dma_tile(Ji, j2, rem2, wv, lane, lds[nb]);
    }
    // token words for tile s+2 (exactly 3 loads)
    tok_words<USET>(tokP, Xtok, j0 + 2 * TJ, jbeg, jend, n, twn);
    // gather tile s (overlaps 2 tiles of in-flight DMA + 2 tiles of tokens)
    #pragma unroll
    for (int jl = 0; jl < TJ; ++jl) {
      if (jl >= rem) break;            // block-uniform
      const float* p = lds[cur] + bo[jl];
      #pragma unroll
      for (int a = 0; a < QQ; ++a) lg[a] += p[a * PLANE];
    }
    // unpack bo for tile s+1 (words loaded LAST iteration -> latency covered
    // by the gather above); shift prefetched words
    #pragma unroll
    for (int k = 0; k < TJ; ++k)
      bo[k] = k * QQ + (int)((twc[k >> 2] >> ((k & 3) * 8)) & 0xFF);
    #pragma unroll
    for (int wi = 0; wi < 3; ++wi) twc[wi] = twn[wi];
    tile_barrier(wv);                  // drains prior iteration's vmem only
    ++cur; if (cur == NBUF) cur = 0;
  }

  if (MONO) {
    const float* hi = h + i * QQ;
    float mx = -3.0e38f;
    #pragma unroll
    for (int a = 0; a < QQ; ++a) { lg[a] += hi[a]; mx = fmaxf(mx, lg[a]); }
    float sme = 0.0f;
    #pragma unroll
    for (int a = 0; a < QQ; ++a) sme += expf(lg[a] - mx);
    const float contrib = w[n] * (mx + logf(sme));
    const float tot = block_reduce_sum<NWAVE>(contrib);
    if (t == 0) atomicAdd(acc + SLOT_LZ + (iI & 63), tot);
  } else {
    float* dst = slab + (((size_t)y * NS + iI) * QQ) * MM + n;
    #pragma unroll
    for (int a = 0; a < QQ; ++a) dst[a * MM] = lg[a];
  }
}

// ---------------------------------------------------------------------------
// jsum body: sum(J^2) stream + sum(J*fij) prefix rows, grid-strided by jb.
// ---------------------------------------------------------------------------
__device__ __forceinline__ void jsum_body(
    const float* __restrict__ J, const float* __restrict__ fij,
    float* __restrict__ acc, int jb) {
  const int t = threadIdx.x;
  const float4* __restrict__ J4 = (const float4*)J;
  float j2 = 0.0f;
  for (int f = jb * BT + t; f < (LL * QQ * LL * QQ / 4); f += NB_JS * BT) {
    const float4 v = J4[f];
    j2 += v.x * v.x + v.y * v.y + v.z * v.z + v.w * v.w;
  }
  float e = 0.0f;
  for (int r = jb; r < NS * QQ; r += NB_JS) {
    const int iI = r / QQ;
    const int a  = r - iI * QQ;
    const int i  = START + iI;
    const size_t base = (size_t)i * (QQ * LL * QQ) + (size_t)a * (LL * QQ);
    const float4* __restrict__ Jb = (const float4*)(J + base);
    const float4* __restrict__ Fb = (const float4*)(fij + base);
    const int lim  = i * QQ;
    const int lim4 = lim >> 2;
    for (int f = t; f < lim4; f += BT) {
      const float4 v = Jb[f], u = Fb[f];
      e += v.x * u.x + v.y * u.y + v.z * u.z + v.w * u.w;
    }
    const int rem = lim & 3;
    if (t < rem) {
      const int p = lim4 * 4 + t;
      e += (J + base)[p] * (fij + base)[p];
    }
  }
  const float tj2 = block_reduce_sum<NWAVE>(j2);
  const float te  = block_reduce_sum<NWAVE>(e);
  if (t == 0) {
    atomicAdd(acc + SLOT_J2 + (jb & 63), tj2);
    atomicAdd(acc + SLOT_E  + (jb & 63), te);
  }
}

// ---------------------------------------------------------------------------
// Fused kernel: blocks [0, NB_P1) run p1 (latency/LDS-bound, long —
// dispatched first); blocks [NB_P1, NB_P1+NB_JS) run jsum (HBM-bound
// fillers). Disjoint pipes overlap on the same CUs; jsum fills p1's tail.
// ---------------------------------------------------------------------------
__global__ __launch_bounds__(BT) void kern_mega(
    const float* __restrict__ J, const float* __restrict__ fij,
    const uint32_t* __restrict__ tokP, float* __restrict__ slab,
    float* __restrict__ acc) {
  __shared__ float lds[NBUF][TILE_FLOATS];
  const int bx = blockIdx.x;
  if (bx < NB_P1) {
    const int iI  = bx % NS;
    const int sub = bx / NS;           // 0..3
    logz_body<false, 1>(J, tokP, nullptr, nullptr, nullptr, slab, acc,
                        iI, sub & 1, sub >> 1, lds);
  } else {
    jsum_body(J, fij, acc, bx - NB_P1);
  }
}

// Fallback kernels (ws too small for slab)
__global__ __launch_bounds__(BT) void kern_logz_mono_t(
    const float* __restrict__ J, const uint32_t* __restrict__ tokP,
    const float* __restrict__ h, const float* __restrict__ w,
    float* __restrict__ acc) {
  __shared__ float lds[NBUF][TILE_FLOATS];
  logz_body<true, 1>(J, tokP, nullptr, h, w, nullptr, acc,
                     blockIdx.x, 0, blockIdx.z, lds);
}

__global__ __launch_bounds__(BT) void kern_logz_mono_x(
    const float* __restrict__ J, const int* __restrict__ Xtok,
    const float* __restrict__ h, const float* __restrict__ w,
    float* __restrict__ acc) {
  __shared__ float lds[NBUF][TILE_FLOATS];
  logz_body<true, 0>(J, nullptr, Xtok, h, w, nullptr, acc,
                     blockIdx.x, 0, blockIdx.z, lds);
}

__global__ __launch_bounds__(BT) void kern_jsum(
    const float* __restrict__ J, const float* __restrict__ fij,
    float* __restrict__ acc) {
  jsum_body(J, fij, acc, blockIdx.x);
}

// ---------------------------------------------------------------------------
// Phase 2: combine j-half partials, logsumexp, weighted sum. Fence-free
// (the R1 fused epilogue's __threadfence cost ~the mega win; reverted).
// ---------------------------------------------------------------------------
__global__ __launch_bounds__(128) void kern_logz_p2(
    const float* __restrict__ slab, const float* __restrict__ h,
    const float* __restrict__ w, float* __restrict__ acc) {
  const int iI = blockIdx.x;
  const int n  = blockIdx.y * 128 + threadIdx.x;
  const float* s0 = slab + ((size_t)iI * QQ) * MM + n;
  const float* s1 = slab + (((size_t)NS + iI) * QQ) * MM + n;
  const float* hi = h + (START + iI) * QQ;
  float lg[QQ];
  float mx = -3.0e38f;
  #pragma unroll
  for (int a = 0; a < QQ; ++a) {
    lg[a] = s0[a * MM] + s1[a * MM] + hi[a];
    mx = fmaxf(mx, lg[a]);
  }
  float sme = 0.0f;
  #pragma unroll
  for (int a = 0; a < QQ; ++a) sme += expf(lg[a] - mx);
  float v = w[n] * (mx + logf(sme));
  #pragma unroll
  for (int off = 32; off > 0; off >>= 1) v += __shfl_down(v, off, 64);
  __shared__ float sm[2];
  if ((threadIdx.x & 63) == 0) sm[threadIdx.x >> 6] = v;
  __syncthreads();
  if (threadIdx.x == 0)
    atomicAdd(acc + SLOT_LZ + ((iI * 8 + blockIdx.y) & 63), sm[0] + sm[1]);
}

// ---------------------------------------------------------------------------
// Token packing: tokP[jq][n] = X[n][4jq..4jq+3] packed as 4 bytes.
// Block 0 also zeroes the 1 KB accumulator region (replaces hipMemsetAsync).
// ---------------------------------------------------------------------------
__global__ __launch_bounds__(256) void kern_tokP(
    const int* __restrict__ X, uint32_t* __restrict__ tokP,
    float* __restrict__ acc) {
  const int idx = blockIdx.x * 256 + threadIdx.x;
  if (blockIdx.x == 0) acc[threadIdx.x] = 0.0f;
  if (idx < (LL / 4) * MM) {
    const int jq = idx / MM;
    const int n  = idx - jq * MM;
    const int4 x = *reinterpret_cast<const int4*>(X + n * LL + 4 * jq);
    tokP[idx] = (uint32_t)x.x | ((uint32_t)x.y << 8)
              | ((uint32_t)x.z << 16) | ((uint32_t)x.w << 24);
  }
}

// ---------------------------------------------------------------------------
// Final combine: slot sums + h-side terms + weight normalization.
// ---------------------------------------------------------------------------
__global__ __launch_bounds__(256) void kern_final(
    const float* __restrict__ h, const float* __restrict__ fi,
    const float* __restrict__ w, const float* __restrict__ acc,
    float* __restrict__ out) {
  const int t = threadIdx.x;
  const float sj2 = block_reduce_sum<4>(t < 64 ? acc[SLOT_J2 + t] : 0.0f);
  const float se  = block_reduce_sum<4>(t < 64 ? acc[SLOT_E + t] : 0.0f);
  const float slz = block_reduce_sum<4>(t < 64 ? acc[SLOT_LZ + t] : 0.0f);
  float hs = 0.0f, eh = 0.0f, ws = 0.0f;
  for (int idx = t; idx < LL * QQ; idx += 256) {
    const float hv = h[idx];
    hs += hv * hv;
    if (idx >= START * QQ) eh += fi[idx] * hv;
  }
  for (int idx = t; idx < MM; idx += 256) ws += w[idx];
  const float ths = block_reduce_sum<4>(hs);
  const float teh = block_reduce_sum<4>(eh);
  const float tws = block_reduce_sum<4>(ws);
  if (t == 0) {
    const float energy = teh + se;
    const float nll = slz / tws - energy;
    out[0] = nll + RGH * ths + RGJ * sj2;
    out[1] = nll;
  }
}

extern "C" void kernel_launch(void* const* d_in, const int* in_sizes, int n_in,
                              void* d_out, int out_size, void* d_ws, size_t ws_size,
                              hipStream_t stream) {
  const int*   Xtok = (const int*)  d_in[0];
  const float* wts  = (const float*)d_in[1];
  const float* fi   = (const float*)d_in[2];
  const float* fij  = (const float*)d_in[3];
  const float* h    = (const float*)d_in[4];
  const float* J    = (const float*)d_in[5];
  float* out  = (float*)d_out;
  float* acc  = (float*)d_ws;
  uint32_t* tokP = (uint32_t*)((char*)d_ws + TOKP_OFF);
  float* slab = (float*)((char*)d_ws + SLAB_OFF);

  if (ws_size >= WS_FULL) {
    kern_tokP<<<((LL / 4) * MM + 255) / 256, 256, 0, stream>>>(Xtok, tokP, acc);
    kern_mega<<<NB_P1 + NB_JS, BT, 0, stream>>>(J, fij, tokP, slab, acc);
    kern_logz_p2<<<dim3(NS, 8), 128, 0, stream>>>(slab, h, wts, acc);
    kern_final<<<1, 256, 0, stream>>>(h, fi, wts, acc, out);
  } else if (ws_size >= WS_TOK) {
    kern_tokP<<<((LL / 4) * MM + 255) / 256, 256, 0, stream>>>(Xtok, tokP, acc);
    kern_jsum<<<NB_JS, BT, 0, stream>>>(J, fij, acc);
    kern_logz_mono_t<<<dim3(NS, 1, 2), BT, 0, stream>>>(J, tokP, h, wts, acc);
    kern_final<<<1, 256, 0, stream>>>(h, fi, wts, acc, out);
  } else {
    hipMemsetAsync(d_ws, 0, 1024, stream);
    kern_jsum<<<NB_JS, BT, 0, stream>>>(J, fij, acc);
    kern_logz_mono_x<<<dim3(NS, 1, 2), BT, 0, stream>>>(J, Xtok, h, wts, acc);
    kern_final<<<1, 256, 0, stream>>>(h, fi, wts, acc, out);
  }
}

// Round 3
// 186.129 us; speedup vs baseline: 1.1210x; 1.0070x over previous
//
#include <hip/hip_runtime.h>
#include <cstdint>

// Problem constants (from the reference)
#define LL    200
#define QQ    21
#define MM    1024
#define START 133        // 2*L//3
#define NS    67         // L - START
#define RGH   0.01f
#define RGJ   0.01f

// ws layout:
//   [0, 1024)              : accumulator slots (3 x 64 fp32)
//   [1024, +TOKP)          : tokP packed tokens, 4 j per dword, [jq][n]
//                            (52 words: 50 real + 2 pad, pad never consumed)
//   [TOKP end, +SLAB)      : logit slab [iI][a][n], atomic-accumulated
#define SLOT_J2  0
#define SLOT_E   64
#define SLOT_LZ  128
#define TOKP_W   52
#define TOKP_OFF 1024
#define TOKP_BYTES ((size_t)TOKP_W * MM * 4)
#define SLAB_OFF (TOKP_OFF + TOKP_BYTES)
#define SLAB_FLOATS ((size_t)NS * QQ * MM)
#define SLAB_BYTES (SLAB_FLOATS * 4)
#define WS_FULL (SLAB_OFF + SLAB_BYTES)
#define WS_TOK  SLAB_OFF

// LDS tile: raw a-major copy of J[i, a, j0:j0+TJ, :]. TJ=12 -> plane = 252
// dwords (1008 B = exactly 63 16B chunks):
//  - DMA: 63-lane global_load_lds(16B) fills a plane exactly
//  - gather: ds_read2_b32 pairs planes (a, a+1): offsets 0/252 dwords both
//    fit the 8-bit read2 fields (PLANE<=255 is load-bearing!). 11 LDS
//    instrs per (n,j) instead of 21. Lanes differ only in b -> <=21
//    consecutive dwords -> conflict-free (measured 0 conflicts).
#define TJ 12
#define PLANE 252
#define TILE_FLOATS (QQ * PLANE)       // 5292 floats = 21168 B
#define NBUF 3
#define BT 512
#define NWAVE 8

// Balanced p1 schedule: flatten (z, site, j-quad) -> [0, T_ALL) and cut into
// NB_P1 equal ranges (~22 quads). A site has >=34 quads > 22 -> each block
// spans <=2 sites (<=2 pipelined segments), flushed by atomicAdd into slab.
#define NB_P1 256
#define NB_JS 512
#define NB_TOKP 512

typedef const uint32_t __attribute__((address_space(1)))* gq_t;
typedef uint32_t __attribute__((address_space(3)))* lq_t;

template <int NW>
__device__ __forceinline__ float block_reduce_sum(float v) {
  __shared__ float sm[NW];
  #pragma unroll
  for (int off = 32; off > 0; off >>= 1) v += __shfl_down(v, off, 64);
  const int lane = threadIdx.x & 63;
  const int wv   = threadIdx.x >> 6;
  __syncthreads();
  if (lane == 0) sm[wv] = v;
  __syncthreads();
  float r = 0.0f;
  if (threadIdx.x == 0) {
    #pragma unroll
    for (int k = 0; k < NW; ++k) r += sm[k];
  }
  return r;  // valid in thread 0 only
}

// ---------------------------------------------------------------------------
// DMA one tile (21 a-planes) into LDS. Wave wv owns planes {wv, wv+8, ...}:
// waves 0-4 issue 3 global_load_lds, waves 5-7 issue 2 (lane guard always has
// active lanes in every wave, so the per-wave vmem count is exact).
// Fake tiles pass rem=1 (6 lanes, 96 B/plane) to keep counts uniform cheaply.
// ---------------------------------------------------------------------------
__device__ __forceinline__ void dma_tile(
    const float* __restrict__ Ji, int j0, int rem, int wv, int lane,
    float* __restrict__ tile) {
  const int nlanes = (rem * QQ + 3) >> 2;      // 63 for rem=12; >=6 always
  if (lane < nlanes) {
    for (int a = wv; a < QQ; a += NWAVE) {
      const float* g = Ji + a * (LL * QQ) + j0 * QQ + lane * 4;
      __builtin_amdgcn_global_load_lds((gq_t)g, (lq_t)(tile + a * PLANE),
                                       16, 0, 0);
    }
  }
}

// ---------------------------------------------------------------------------
// Load the 3 packed token words covering tile at j0 (12 j's, j0 % 4 == 0).
// Always exactly 3 vmem instructions (CSE across iterations is blocked by the
// asm "memory" clobbers in the barriers):
//   USET=1: 3 x dword from tokP;  USET=0: 3 x dwordx4 from X, packed in VALU.
// Fully-fake tiles (j0 >= jend) reload tile-0's words.
// ---------------------------------------------------------------------------
template <int USET>
__device__ __forceinline__ void tok_words(
    const uint32_t* __restrict__ tokP, const int* __restrict__ Xtok,
    int j0, int jbeg, int jend, int n, uint32_t (&tw)[3]) {
  const int wbase = ((j0 < jend) ? j0 : jbeg) >> 2;
  #pragma unroll
  for (int wi = 0; wi < 3; ++wi) {
    int wq = wbase + wi;
    if constexpr (USET) {
      tw[wi] = tokP[wq * MM + n];        // words 50/51 = pad, never consumed
    } else {
      if (wq >= LL / 4) wq -= (LL / 4 - 1);   // keep in-bounds, distinct
      const int4 x = *reinterpret_cast<const int4*>(Xtok + n * LL + 4 * wq);
      tw[wi] = (uint32_t)x.x | ((uint32_t)x.y << 8)
             | ((uint32_t)x.z << 16) | ((uint32_t)x.w << 24);
    }
  }
}

// Counted-wait barrier. Immediate = vmem issued per iteration (d dma + 3
// tok): drains ALL prior-iteration vmem regardless of intra-iteration issue
// order while keeping this iteration's dma(s+2)+tok(s+2) in flight across
// the barrier (depth-2 pipeline).
__device__ __forceinline__ void tile_barrier(int wv) {
  if (wv < 5) asm volatile("s_waitcnt vmcnt(6)" ::: "memory");
  else        asm volatile("s_waitcnt vmcnt(5)" ::: "memory");
  __builtin_amdgcn_s_barrier();
  __builtin_amdgcn_sched_barrier(0);
}

// ---------------------------------------------------------------------------
// One pipelined segment: accumulate lg[a] += J[i,a,j,b(n,j)] over
// j in [jbeg, jend), jbeg % 4 == 0. Triple-buffered DMA, depth-2 token
// prefetch, gather via ds_read2_b32 plane-pairs.
// ---------------------------------------------------------------------------
template <int USET>
__device__ __forceinline__ void logz_seg(
    const float* __restrict__ Ji, const uint32_t* __restrict__ tokP,
    const int* __restrict__ Xtok, int jbeg, int jend, int n,
    float (*lds)[TILE_FLOATS], float (&lg)[QQ], int wv, int lane) {
  const int ntiles = (jend - jbeg + TJ - 1) / TJ;   // >= 1
  uint32_t tw0[3], twc[3], twn[3];
  int bo[TJ];

  // Prologue: dma tiles 0,1 (tile1 may be fake), token words tiles 0,1,
  // bo(tile0). One full drain per segment, then counted waits only.
  dma_tile(Ji, jbeg, min(TJ, jend - jbeg), wv, lane, lds[0]);
  { int j1 = jbeg + TJ, r1 = jend - j1;
    if (r1 <= 0) { j1 = jbeg; r1 = 1; } else if (r1 > TJ) r1 = TJ;
    dma_tile(Ji, j1, r1, wv, lane, lds[1]); }
  tok_words<USET>(tokP, Xtok, jbeg, jbeg, jend, n, tw0);
  tok_words<USET>(tokP, Xtok, jbeg + TJ, jbeg, jend, n, twc);
  #pragma unroll
  for (int k = 0; k < TJ; ++k)
    bo[k] = k * QQ + (int)((tw0[k >> 2] >> ((k & 3) * 8)) & 0xFF);
  asm volatile("s_waitcnt vmcnt(0)" ::: "memory");
  __builtin_amdgcn_s_barrier();
  __builtin_amdgcn_sched_barrier(0);

  int cur = 0;
  for (int s = 0; s < ntiles; ++s) {
    const int j0  = jbeg + s * TJ;
    const int rem = min(TJ, jend - j0);
    // dma tile s+2 (fake rem=1 past-the-end keeps per-wave counts uniform)
    { int j2 = j0 + 2 * TJ, r2 = jend - j2;
      if (r2 <= 0) { j2 = jbeg; r2 = 1; } else if (r2 > TJ) r2 = TJ;
      int nb = cur + 2; if (nb >= NBUF) nb -= NBUF;
      dma_tile(Ji, j2, r2, wv, lane, lds[nb]); }
    // token words for tile s+2 (exactly 3 loads)
    tok_words<USET>(tokP, Xtok, j0 + 2 * TJ, jbeg, jend, n, twn);
    // gather tile s: per j, 10 x ds_read2_b32 (plane pairs) + 1 x ds_read_b32
    const float* tile = lds[cur];
    #pragma unroll
    for (int jl = 0; jl < TJ; ++jl) {
      if (jl >= rem) break;            // block-uniform
      const float* p = tile + bo[jl];
      #pragma unroll
      for (int k = 0; k < 10; ++k) {
        int o = k * 2 * PLANE;
        asm("" : "+v"(o));             // opaque offset -> forces read2 fuse 0/252
        const float x = p[o], y = p[o + PLANE];
        lg[2 * k]     += x;
        lg[2 * k + 1] += y;
      }
      lg[20] += p[20 * PLANE];         // odd plane: imm-offset b32
    }
    // unpack bo for tile s+1 (words loaded LAST iteration); shift prefetch
    #pragma unroll
    for (int k = 0; k < TJ; ++k)
      bo[k] = k * QQ + (int)((twc[k >> 2] >> ((k & 3) * 8)) & 0xFF);
    #pragma unroll
    for (int wi = 0; wi < 3; ++wi) twc[wi] = twn[wi];
    tile_barrier(wv);                  // counted wait — NO vmcnt(0) drain
    ++cur; if (cur == NBUF) cur = 0;
  }
}

// ---------------------------------------------------------------------------
// p1 block: balanced quad-schedule. Block bx owns quad range
// [bx*T/256, (bx+1)*T/256) of the flattened (z, site, quad) space; runs <=2
// segments and atomic-flushes lg into slab[site][a][n].
// ---------------------------------------------------------------------------
__device__ __forceinline__ void p1_block(
    const float* __restrict__ J, const uint32_t* __restrict__ tokP,
    float* __restrict__ slab, int bx, float (*lds)[TILE_FLOATS]) {
  const int t = threadIdx.x, lane = t & 63, wv = t >> 6;

  int Tz = 0;                          // constant-folds (NS, START constants)
  #pragma unroll
  for (int s2 = 0; s2 < NS; ++s2) Tz += (START + s2 + 3) >> 2;
  const int T2 = 2 * Tz;

  int g  = (bx * T2) / NB_P1;
  const int g1 = ((bx + 1) * T2) / NB_P1;
  int z  = (g >= Tz) ? 1 : 0;
  int gz = g - (z ? Tz : 0);
  int iI = 0, pref = 0;
  while (pref + ((START + iI + 3) >> 2) <= gz) {
    pref += (START + iI + 3) >> 2;
    ++iI;
  }
  int qlo = gz - pref;

  float lg[QQ];
  #pragma unroll
  for (int a = 0; a < QQ; ++a) lg[a] = 0.0f;

  while (g < g1) {
    const int i    = START + iI;
    const int qcap = (i + 3) >> 2;
    int qhi = qlo + (g1 - g);
    if (qhi > qcap) qhi = qcap;
    const int jbeg = qlo * 4;
    int jend = qhi * 4; if (jend > i) jend = i;
    const int n = z * BT + t;
    const float* Ji = J + (size_t)i * (QQ * LL * QQ);

    logz_seg<1>(Ji, tokP, nullptr, jbeg, jend, n, lds, lg, wv, lane);

    float* dst = slab + ((size_t)iI * QQ) * MM + n;
    #pragma unroll
    for (int a = 0; a < QQ; ++a) { atomicAdd(dst + a * MM, lg[a]); lg[a] = 0.0f; }

    g += qhi - qlo;
    qlo = 0; ++iI;
    if (iI == NS) { iI = 0; z = 1; }
  }
}

// ---------------------------------------------------------------------------
// jsum body: sum(J^2) stream + sum(J*fij) prefix rows, grid-strided by jb.
// ---------------------------------------------------------------------------
__device__ __forceinline__ void jsum_body(
    const float* __restrict__ J, const float* __restrict__ fij,
    float* __restrict__ acc, int jb) {
  const int t = threadIdx.x;
  const float4* __restrict__ J4 = (const float4*)J;
  float j2 = 0.0f;
  for (int f = jb * BT + t; f < (LL * QQ * LL * QQ / 4); f += NB_JS * BT) {
    const float4 v = J4[f];
    j2 += v.x * v.x + v.y * v.y + v.z * v.z + v.w * v.w;
  }
  float e = 0.0f;
  for (int r = jb; r < NS * QQ; r += NB_JS) {
    const int iI = r / QQ;
    const int a  = r - iI * QQ;
    const int i  = START + iI;
    const size_t base = (size_t)i * (QQ * LL * QQ) + (size_t)a * (LL * QQ);
    const float4* __restrict__ Jb = (const float4*)(J + base);
    const float4* __restrict__ Fb = (const float4*)(fij + base);
    const int lim  = i * QQ;
    const int lim4 = lim >> 2;
    for (int f = t; f < lim4; f += BT) {
      const float4 v = Jb[f], u = Fb[f];
      e += v.x * u.x + v.y * u.y + v.z * u.z + v.w * u.w;
    }
    const int rem = lim & 3;
    if (t < rem) {
      const int p = lim4 * 4 + t;
      e += (J + base)[p] * (fij + base)[p];
    }
  }
  const float tj2 = block_reduce_sum<NWAVE>(j2);
  const float te  = block_reduce_sum<NWAVE>(e);
  if (t == 0) {
    atomicAdd(acc + SLOT_J2 + (jb & 63), tj2);
    atomicAdd(acc + SLOT_E  + (jb & 63), te);
  }
}

// ---------------------------------------------------------------------------
// Fused kernel: blocks [0, NB_P1) run p1 (LDS-issue-bound, ~equal length —
// dispatched first, one per CU); blocks [NB_P1, NB_P1+NB_JS) run jsum
// (HBM-bound fillers) on the second block slot of each CU.
// ---------------------------------------------------------------------------
__global__ __launch_bounds__(BT) void kern_mega(
    const float* __restrict__ J, const float* __restrict__ fij,
    const uint32_t* __restrict__ tokP, float* __restrict__ slab,
    float* __restrict__ acc) {
  __shared__ float lds[NBUF][TILE_FLOATS];
  const int bx = blockIdx.x;
  if (bx < NB_P1) p1_block(J, tokP, slab, bx, lds);
  else            jsum_body(J, fij, acc, bx - NB_P1);
}

// ---------------------------------------------------------------------------
// Fallback (ws too small for slab): full-range mono blocks with in-kernel
// logsumexp. Grid (NS, 1, 2), z = blockIdx.z.
// ---------------------------------------------------------------------------
template <int USET>
__device__ __forceinline__ void mono_body(
    const float* __restrict__ J, const uint32_t* __restrict__ tokP,
    const int* __restrict__ Xtok, const float* __restrict__ h,
    const float* __restrict__ w, float* __restrict__ acc,
    float (*lds)[TILE_FLOATS]) {
  const int iI = blockIdx.x;
  const int i  = START + iI;
  const int t = threadIdx.x, lane = t & 63, wv = t >> 6;
  const int n = blockIdx.z * BT + t;
  float lg[QQ];
  #pragma unroll
  for (int a = 0; a < QQ; ++a) lg[a] = 0.0f;
  logz_seg<USET>(J + (size_t)i * (QQ * LL * QQ), tokP, Xtok, 0, i, n,
                 lds, lg, wv, lane);
  const float* hi = h + i * QQ;
  float mx = -3.0e38f;
  #pragma unroll
  for (int a = 0; a < QQ; ++a) { lg[a] += hi[a]; mx = fmaxf(mx, lg[a]); }
  float sme = 0.0f;
  #pragma unroll
  for (int a = 0; a < QQ; ++a) sme += expf(lg[a] - mx);
  const float contrib = w[n] * (mx + logf(sme));
  const float tot = block_reduce_sum<NWAVE>(contrib);
  if (t == 0) atomicAdd(acc + SLOT_LZ + (iI & 63), tot);
}

__global__ __launch_bounds__(BT) void kern_logz_mono_t(
    const float* __restrict__ J, const uint32_t* __restrict__ tokP,
    const float* __restrict__ h, const float* __restrict__ w,
    float* __restrict__ acc) {
  __shared__ float lds[NBUF][TILE_FLOATS];
  mono_body<1>(J, tokP, nullptr, h, w, acc, lds);
}

__global__ __launch_bounds__(BT) void kern_logz_mono_x(
    const float* __restrict__ J, const int* __restrict__ Xtok,
    const float* __restrict__ h, const float* __restrict__ w,
    float* __restrict__ acc) {
  __shared__ float lds[NBUF][TILE_FLOATS];
  mono_body<0>(J, nullptr, Xtok, h, w, acc, lds);
}

__global__ __launch_bounds__(BT) void kern_jsum(
    const float* __restrict__ J, const float* __restrict__ fij,
    float* __restrict__ acc) {
  jsum_body(J, fij, acc, blockIdx.x);
}

// ---------------------------------------------------------------------------
// Phase 2: slab + h -> logsumexp -> weighted sum (fence-free).
// ---------------------------------------------------------------------------
__global__ __launch_bounds__(128) void kern_logz_p2(
    const float* __restrict__ slab, const float* __restrict__ h,
    const float* __restrict__ w, float* __restrict__ acc) {
  const int iI = blockIdx.x;
  const int n  = blockIdx.y * 128 + threadIdx.x;
  const float* s0 = slab + ((size_t)iI * QQ) * MM + n;
  const float* hi = h + (START + iI) * QQ;
  float lg[QQ];
  float mx = -3.0e38f;
  #pragma unroll
  for (int a = 0; a < QQ; ++a) {
    lg[a] = s0[a * MM] + hi[a];
    mx = fmaxf(mx, lg[a]);
  }
  float sme = 0.0f;
  #pragma unroll
  for (int a = 0; a < QQ; ++a) sme += expf(lg[a] - mx);
  float v = w[n] * (mx + logf(sme));
  #pragma unroll
  for (int off = 32; off > 0; off >>= 1) v += __shfl_down(v, off, 64);
  __shared__ float sm[2];
  if ((threadIdx.x & 63) == 0) sm[threadIdx.x >> 6] = v;
  __syncthreads();
  if (threadIdx.x == 0)
    atomicAdd(acc + SLOT_LZ + ((iI * 8 + blockIdx.y) & 63), sm[0] + sm[1]);
}

// ---------------------------------------------------------------------------
// Token packing: tokP[jq][n] = X[n][4jq..4jq+3] packed as 4 bytes. Block 0
// zeroes the accumulator slots; all blocks grid-stride-zero the slab
// (atomic-accumulated in mega, so it must start at 0).
// ---------------------------------------------------------------------------
__global__ __launch_bounds__(256) void kern_tokP(
    const int* __restrict__ X, uint32_t* __restrict__ tokP,
    float* __restrict__ slab, float* __restrict__ acc, int zslab) {
  const int idx = blockIdx.x * 256 + threadIdx.x;
  if (blockIdx.x == 0) acc[threadIdx.x] = 0.0f;
  if (idx < (LL / 4) * MM) {
    const int jq = idx / MM;
    const int n  = idx - jq * MM;
    const int4 x = *reinterpret_cast<const int4*>(X + n * LL + 4 * jq);
    tokP[idx] = (uint32_t)x.x | ((uint32_t)x.y << 8)
              | ((uint32_t)x.z << 16) | ((uint32_t)x.w << 24);
  }
  if (zslab) {
    float4* s4 = (float4*)slab;
    const int nf4 = (int)(SLAB_FLOATS / 4);
    for (int q = idx; q < nf4; q += NB_TOKP * 256)
      s4[q] = make_float4(0.f, 0.f, 0.f, 0.f);
  }
}

// ---------------------------------------------------------------------------
// Final combine: slot sums + h-side terms + weight normalization.
// ---------------------------------------------------------------------------
__global__ __launch_bounds__(256) void kern_final(
    const float* __restrict__ h, const float* __restrict__ fi,
    const float* __restrict__ w, const float* __restrict__ acc,
    float* __restrict__ out) {
  const int t = threadIdx.x;
  const float sj2 = block_reduce_sum<4>(t < 64 ? acc[SLOT_J2 + t] : 0.0f);
  const float se  = block_reduce_sum<4>(t < 64 ? acc[SLOT_E + t] : 0.0f);
  const float slz = block_reduce_sum<4>(t < 64 ? acc[SLOT_LZ + t] : 0.0f);
  float hs = 0.0f, eh = 0.0f, ws = 0.0f;
  for (int idx = t; idx < LL * QQ; idx += 256) {
    const float hv = h[idx];
    hs += hv * hv;
    if (idx >= START * QQ) eh += fi[idx] * hv;
  }
  for (int idx = t; idx < MM; idx += 256) ws += w[idx];
  const float ths = block_reduce_sum<4>(hs);
  const float teh = block_reduce_sum<4>(eh);
  const float tws = block_reduce_sum<4>(ws);
  if (t == 0) {
    const float energy = teh + se;
    const float nll = slz / tws - energy;
    out[0] = nll + RGH * ths + RGJ * sj2;
    out[1] = nll;
  }
}

extern "C" void kernel_launch(void* const* d_in, const int* in_sizes, int n_in,
                              void* d_out, int out_size, void* d_ws, size_t ws_size,
                              hipStream_t stream) {
  const int*   Xtok = (const int*)  d_in[0];
  const float* wts  = (const float*)d_in[1];
  const float* fi   = (const float*)d_in[2];
  const float* fij  = (const float*)d_in[3];
  const float* h    = (const float*)d_in[4];
  const float* J    = (const float*)d_in[5];
  float* out  = (float*)d_out;
  float* acc  = (float*)d_ws;
  uint32_t* tokP = (uint32_t*)((char*)d_ws + TOKP_OFF);
  float* slab = (float*)((char*)d_ws + SLAB_OFF);

  if (ws_size >= WS_FULL) {
    kern_tokP<<<NB_TOKP, 256, 0, stream>>>(Xtok, tokP, slab, acc, 1);
    kern_mega<<<NB_P1 + NB_JS, BT, 0, stream>>>(J, fij, tokP, slab, acc);
    kern_logz_p2<<<dim3(NS, 8), 128, 0, stream>>>(slab, h, wts, acc);
    kern_final<<<1, 256, 0, stream>>>(h, fi, wts, acc, out);
  } else if (ws_size >= WS_TOK) {
    kern_tokP<<<NB_TOKP, 256, 0, stream>>>(Xtok, tokP, nullptr, acc, 0);
    kern_jsum<<<NB_JS, BT, 0, stream>>>(J, fij, acc);
    kern_logz_mono_t<<<dim3(NS, 1, 2), BT, 0, stream>>>(J, tokP, h, wts, acc);
    kern_final<<<1, 256, 0, stream>>>(h, fi, wts, acc, out);
  } else {
    hipMemsetAsync(d_ws, 0, 1024, stream);
    kern_jsum<<<NB_JS, BT, 0, stream>>>(J, fij, acc);
    kern_logz_mono_x<<<dim3(NS, 1, 2), BT, 0, stream>>>(J, Xtok, h, wts, acc);
    kern_final<<<1, 256, 0, stream>>>(h, fi, wts, acc, out);
  }
}